// Round 12
// baseline (534.527 us; speedup 1.0000x reference)
//
#include <hip/hip_runtime.h>

#define BN_EPS 1e-5f

typedef _Float16 half_t;
typedef _Float16 half2_t __attribute__((ext_vector_type(2)));

#define NBK_MAX 512   // max dst-buckets (256 dsts each) -> n <= 131072
#define EPB 8192      // edges per block in bucket scatter
#define REC 64        // xl record: 64 halves = 128 B, line-aligned
#define CAP 5120      // fixed per-bucket capacity (mean ~4350, +11 sigma)

#if __has_builtin(__builtin_amdgcn_fdot2)
#define DOT2(a, b, c) __builtin_amdgcn_fdot2((a), (b), (c), false)
#else
#define DOT2(a, b, c) fmaf((float)(a).x, (float)(b).x, fmaf((float)(a).y, (float)(b).y, (c)))
#endif

// ---------------- bucketed CSR build (fixed-capacity buckets, packed entries) ----------------

// K1: two-pass over this block's ei slice (L2-hot): count per bucket, reserve, place.
// bstage entry = (src << 8) | (dst & 255); bucket implied by slot (strided by CAP).
__global__ void __launch_bounds__(256) bucket_scatter_kernel(
    const int* __restrict__ ei, int* __restrict__ bcur, unsigned* __restrict__ bstage,
    int E, int etot, int nbk) {
  __shared__ int lh[NBK_MAX], lbase[NBK_MAX];
  int base = blockIdx.x * EPB;
  int cnt = min(EPB, etot - base);
  for (int i = threadIdx.x; i < nbk; i += 256) lh[i] = 0;
  __syncthreads();
  for (int i = threadIdx.x; i < cnt; i += 256) {
    int e = base + i;
    int d = (e < E) ? ei[E + e] : (e - E);
    atomicAdd(&lh[d >> 8], 1);
  }
  __syncthreads();
  for (int i = threadIdx.x; i < nbk; i += 256) {
    int c = lh[i];
    lbase[i] = c ? (i * CAP + atomicAdd(&bcur[i], c)) : 0;
    lh[i] = 0;  // becomes local run cursor
  }
  __syncthreads();
  for (int i = threadIdx.x; i < cnt; i += 256) {
    int e = base + i;
    int s, d;
    if (e < E) { s = ei[e]; d = ei[E + e]; } else { s = e - E; d = s; }
    int b = d >> 8;
    int r = atomicAdd(&lh[b], 1);
    bstage[lbase[b] + r] = ((unsigned)s << 8) | (unsigned)(d & 255);
  }
}

// K2: per-bucket degree count + in-bucket scan -> start/deg, then LDS-cursor placement
__global__ void __launch_bounds__(256) csr_finalize_kernel(
    const unsigned* __restrict__ bstage, const int* __restrict__ bcur,
    int* __restrict__ start, int* __restrict__ deg, int* __restrict__ csrc, int n) {
  __shared__ int ld[256];
  __shared__ int wsum[4];
  int b = blockIdx.x, tid = threadIdx.x;
  int d0 = b << 8;
  int p0 = b * CAP;
  int bc = bcur[b];
  ld[tid] = 0;
  __syncthreads();
  for (int p = p0 + tid; p < p0 + bc; p += 256)
    atomicAdd(&ld[bstage[p] & 255u], 1);
  __syncthreads();
  int v = ld[tid];
  int lane = tid & 63, wid = tid >> 6;
  int incl = v;
#pragma unroll
  for (int off = 1; off < 64; off <<= 1) {
    int t = __shfl_up(incl, off, 64);
    if (lane >= off) incl += t;
  }
  if (lane == 63) wsum[wid] = incl;
  __syncthreads();
  if (tid == 0) {
    int s = 0;
#pragma unroll
    for (int w = 0; w < 4; w++) { int t = wsum[w]; wsum[w] = s; s += t; }
  }
  __syncthreads();
  incl += wsum[wid];
  int st = p0 + incl - v;
  int i = d0 + tid;
  if (i < n) { start[i] = st; deg[i] = v; }
  __syncthreads();
  ld[tid] = st;  // cursor
  __syncthreads();
  for (int p = p0 + tid; p < p0 + bc; p += 256) {
    unsigned sd = bstage[p];
    int pos = atomicAdd(&ld[sd & 255u], 1);
    csrc[pos] = (int)(sd >> 8);
  }
}

// ---------------- node transform ----------------
// Input IT = float (layer 1) or half_t (hb). Each thread computes JT outputs for one node.
// xl (fp16, [n][REC] 128B records, head h at half-offset h*C) = x@Wl+bl
// xr (fp16, [n][HC]) = x@Wr+br

template <int CIN, int H, int C, int JT, typename IT>
__global__ void __launch_bounds__(256) transform_kernel(
    const IT* __restrict__ x, const float* __restrict__ Wl, const float* __restrict__ Wr,
    const float* __restrict__ bl, const float* __restrict__ br, half_t* __restrict__ xl,
    half_t* __restrict__ xr, int n) {
  constexpr int HC = H * C;
  constexpr int TPN = HC / JT;  // threads per node
  __shared__ float sW[2 * CIN * HC];
  for (int i = threadIdx.x; i < CIN * HC; i += blockDim.x) {
    sW[i] = Wl[i];
    sW[CIN * HC + i] = Wr[i];
  }
  __syncthreads();
  int idx = blockIdx.x * blockDim.x + threadIdx.x;
  if (idx >= n * TPN) return;
  int node = idx / TPN;
  int j0 = (idx - node * TPN) * JT;

  float al[JT], ar[JT];
#pragma unroll
  for (int jj = 0; jj < JT; jj++) {
    al[jj] = bl[j0 + jj];
    ar[jj] = br[j0 + jj];
  }
  float xrow[CIN];
  if constexpr (sizeof(IT) == 4) {
    const float2* xp = reinterpret_cast<const float2*>((const float*)x + (size_t)node * CIN);
#pragma unroll
    for (int k2 = 0; k2 < CIN / 2; k2++) {
      float2 v = xp[k2];
      xrow[2 * k2] = v.x;
      xrow[2 * k2 + 1] = v.y;
    }
  } else {
    const half2_t* xp = reinterpret_cast<const half2_t*>((const half_t*)x + (size_t)node * CIN);
#pragma unroll
    for (int k2 = 0; k2 < CIN / 2; k2++) {
      half2_t v = xp[k2];
      xrow[2 * k2] = (float)v.x;
      xrow[2 * k2 + 1] = (float)v.y;
    }
  }
#pragma unroll
  for (int k = 0; k < CIN; k++) {
    float xs = xrow[k];
#pragma unroll
    for (int jj = 0; jj < JT; jj++) {
      al[jj] = fmaf(xs, sW[k * HC + j0 + jj], al[jj]);
      ar[jj] = fmaf(xs, sW[CIN * HC + k * HC + j0 + jj], ar[jj]);
    }
  }
#pragma unroll
  for (int jj = 0; jj < JT; jj++) {
    int j = j0 + jj;
    xl[(size_t)node * REC + j] = (half_t)al[jj];   // heads packed: offset h*C+c == j
    xr[(size_t)node * HC + j] = (half_t)ar[jj];
  }
}

// ---------------- fused edge pass ----------------
// G=8 lanes cooperate on one (node, head): lane l takes edges l, l+8, ... (trips =
// ceil(deg/8)), partials combined via 3 in-group __shfl_xor rounds. 8x thread count
// gives TLP to hide gather latency and backfill degree stragglers.
// Packed-half2 math; den f32. MODE 0: +bias,BN  1: +bias,BN,ELU  2: raw. Output fp16.

template <int H, int C, int MODE>
__global__ void __launch_bounds__(256) edge_kernel(
    const half_t* __restrict__ xl, const half_t* __restrict__ xr,
    const int* __restrict__ start, const int* __restrict__ deg,
    const int* __restrict__ csrc, const float* __restrict__ att,
    const float* __restrict__ bias, const float* __restrict__ g,
    const float* __restrict__ be, const float* __restrict__ rm,
    const float* __restrict__ rv, half_t* __restrict__ out, int n) {
  constexpr int HC = H * C;
  constexpr int C2 = C / 2;
  constexpr int G = 8;
  int t = blockIdx.x * blockDim.x + threadIdx.x;
  int gid = t >> 3;  // (node, head) group
  if (gid >= n * H) return;
  int gl = t & (G - 1);
  int node = gid / H;
  int h = gid - node * H;

  const half2_t h2z = {(half_t)0.f, (half_t)0.f};
  const half2_t h2lk = {(half_t)0.2f, (half_t)0.2f};

  half2_t xr_h[C2], att_h[C2], acc[C2];
  const half2_t* xrp = reinterpret_cast<const half2_t*>(xr + (size_t)node * HC + h * C);
#pragma unroll
  for (int i = 0; i < C2; i++) {
    xr_h[i] = xrp[i];
    att_h[i] = half2_t{(half_t)att[h * C + 2 * i], (half_t)att[h * C + 2 * i + 1]};
    acc[i] = h2z;
  }
  float den = 0.f;

  int p0 = start[node];
  int cnt = deg[node];  // >= 1 (self-loop)
  const half_t* xlh = xl + h * C;  // head slice within the 128B record

  int trips = (cnt + G - 1) >> 3;
  int m = gl;
  int idx = csrc[p0 + min(m, cnt - 1)];
  for (int tr = 0; tr < trips; tr++) {
    uint B[C2];
    const uint* xp = reinterpret_cast<const uint*>(xlh + (size_t)idx * REC);
#pragma unroll
    for (int i = 0; i < C2; i++) B[i] = xp[i];
    int mn = m + G;
    int idx_n = csrc[p0 + min(mn, cnt - 1)];  // 1-ahead index prefetch (clamped)

    const half2_t* hp = reinterpret_cast<const half2_t*>(B);
    float e = 0.f;
#pragma unroll
    for (int i = 0; i < C2; i++) {
      half2_t mv = hp[i] + xr_h[i];
      half2_t mp = __builtin_elementwise_max(mv, h2z);
      half2_t mnn = __builtin_elementwise_min(mv, h2z);
      mv = mp + mnn * h2lk;
      e = DOT2(att_h[i], mv, e);
    }
    float ex = (m < cnt) ? __expf(e) : 0.f;
    den += ex;
    half_t exs = (half_t)ex;
    half2_t exv = {exs, exs};
#pragma unroll
    for (int i = 0; i < C2; i++) acc[i] += exv * hp[i];

    m = mn;
    idx = idx_n;
  }

  // in-group reduction (groups are 8 contiguous lanes; xor masks 1,2,4 stay in-group)
#pragma unroll
  for (int mask = 1; mask < G; mask <<= 1) {
    den += __shfl_xor(den, mask, 64);
#pragma unroll
    for (int i = 0; i < C2; i++) {
      int sv = __shfl_xor(__builtin_bit_cast(int, acc[i]), mask, 64);
      acc[i] += __builtin_bit_cast(half2_t, sv);
    }
  }
  if (gl != 0) return;

  float inv = 1.f / den;
  uint* orow = reinterpret_cast<uint*>(out + (size_t)node * HC + h * C);
#pragma unroll
  for (int c2 = 0; c2 < C2; c2++) {
    half2_t ov;
#pragma unroll
    for (int q = 0; q < 2; q++) {
      float a = q ? (float)acc[c2].y : (float)acc[c2].x;
      float val = a * inv;
      if constexpr (MODE != 2) {
        int j = h * C + 2 * c2 + q;
        val += bias[j];
        float sc = g[j] * rsqrtf(rv[j] + BN_EPS);
        val = fmaf(sc, val - rm[j], be[j]);
        if constexpr (MODE == 1) val = (val > 0.f) ? val : expm1f(val);
      }
      if (q) ov.y = (half_t)val; else ov.x = (half_t)val;
    }
    orow[c2] = *reinterpret_cast<uint*>(&ov);
  }
}

// ---------------- layer-4 tail: mean over heads + bias + BN + mu/logvar heads ----------------

__global__ void final_kernel(const half_t* __restrict__ r4, const float* __restrict__ b4,
                             const float* __restrict__ g4, const float* __restrict__ be4,
                             const float* __restrict__ rm4, const float* __restrict__ rv4,
                             const float* __restrict__ Wmu, const float* __restrict__ bmu,
                             const float* __restrict__ Wlv, const float* __restrict__ blv,
                             float* __restrict__ out, int n) {
  int node = blockIdx.x * blockDim.x + threadIdx.x;
  if (node >= n) return;
  float hsum[10];
#pragma unroll
  for (int c = 0; c < 10; c++) hsum[c] = 0.f;
  const half2_t* r = reinterpret_cast<const half2_t*>(r4 + (size_t)node * 50);
  float rv_[50];
#pragma unroll
  for (int i = 0; i < 25; i++) {
    half2_t v = r[i];
    rv_[2 * i] = (float)v.x;
    rv_[2 * i + 1] = (float)v.y;
  }
#pragma unroll
  for (int h = 0; h < 5; h++)
#pragma unroll
    for (int c = 0; c < 10; c++) hsum[c] += rv_[h * 10 + c];
  float hv[10];
#pragma unroll
  for (int c = 0; c < 10; c++) {
    float v = hsum[c] * 0.2f + b4[c];
    float sc = g4[c] * rsqrtf(rv4[c] + BN_EPS);
    hv[c] = fmaf(sc, v - rm4[c], be4[c]);
  }
#pragma unroll
  for (int j = 0; j < 10; j++) {
    float mu = bmu[j], lv = blv[j];
#pragma unroll
    for (int c = 0; c < 10; c++) {
      mu = fmaf(hv[c], Wmu[c * 10 + j], mu);
      lv = fmaf(hv[c], Wlv[c * 10 + j], lv);
    }
    out[(size_t)node * 10 + j] = mu;
    out[(size_t)n * 10 + (size_t)node * 10 + j] = lv;
  }
}

// ---------------- launch ----------------

extern "C" void kernel_launch(void* const* d_in, const int* in_sizes, int n_in,
                              void* d_out, int out_size, void* d_ws, size_t ws_size,
                              hipStream_t stream) {
  const float* x = (const float*)d_in[0];
  const int* ei = (const int*)d_in[1];
  const int n = in_sizes[0] / 22;
  const int E = in_sizes[1] / 2;
  const int etot = E + n;
  const int nbk = (n + 255) >> 8;  // 256-dst buckets

  auto P = [&](int i) { return (const float*)d_in[i]; };

  char* ws = (char*)d_ws;
  size_t off = 0;
  auto alloc = [&](size_t bytes) -> void* {
    void* p = ws + off;
    off += (bytes + 255) & ~(size_t)255;
    return p;
  };
  half_t* xl = (half_t*)alloc((size_t)n * REC * 2);  // 12.8 MB, 128B-aligned records
  half_t* xr = (half_t*)alloc((size_t)n * 54 * 2);   // 10.8 MB
  half_t* hb = (half_t*)alloc((size_t)n * 54 * 2);   // 10.8 MB
  int* start = (int*)alloc((size_t)n * 4);
  int* deg = (int*)alloc((size_t)n * 4);
  int* csrc = (int*)alloc((size_t)nbk * CAP * 4);    // strided buckets (gaps ok)
  int* bcur = (int*)alloc((size_t)nbk * 4);
  // bstage (uint, 8 MB) aliases xl region (only live before transforms run)
  unsigned* bstage = (unsigned*)xl;

  unsigned bb = (unsigned)((etot + EPB - 1) / EPB);
  unsigned nblk = (unsigned)((n + 255) / 256);

  hipMemsetAsync(bcur, 0, (size_t)nbk * 4, stream);
  bucket_scatter_kernel<<<bb, 256, 0, stream>>>(ei, bcur, bstage, E, etot, nbk);
  csr_finalize_kernel<<<(unsigned)nbk, 256, 0, stream>>>(bstage, bcur, start, deg, csrc, n);

  // layer 1: cin=22, H=3, C=18, concat, BN+ELU
  transform_kernel<22, 3, 18, 6, float><<<(unsigned)(((size_t)n * 9 + 255) / 256), 256, 0, stream>>>(
      x, P(2), P(3), P(4), P(5), xl, xr, n);
  edge_kernel<3, 18, 1><<<(unsigned)(((size_t)n * 24 + 255) / 256), 256, 0, stream>>>(
      xl, xr, start, deg, csrc, P(6), P(7), P(8), P(9), P(10), P(11), hb, n);

  // layer 2: cin=54, H=3, C=14, concat, BN
  transform_kernel<54, 3, 14, 6, half_t><<<(unsigned)(((size_t)n * 7 + 255) / 256), 256, 0, stream>>>(
      hb, P(12), P(13), P(14), P(15), xl, xr, n);
  edge_kernel<3, 14, 0><<<(unsigned)(((size_t)n * 24 + 255) / 256), 256, 0, stream>>>(
      xl, xr, start, deg, csrc, P(16), P(17), P(18), P(19), P(20), P(21), hb, n);

  // layer 3: cin=42, H=3, C=12, concat, BN
  transform_kernel<42, 3, 12, 6, half_t><<<(unsigned)(((size_t)n * 6 + 255) / 256), 256, 0, stream>>>(
      hb, P(22), P(23), P(24), P(25), xl, xr, n);
  edge_kernel<3, 12, 0><<<(unsigned)(((size_t)n * 24 + 255) / 256), 256, 0, stream>>>(
      xl, xr, start, deg, csrc, P(26), P(27), P(28), P(29), P(30), P(31), hb, n);

  // layer 4: cin=36, H=5, C=10, mean over heads (raw; epilogue in final_kernel)
  transform_kernel<36, 5, 10, 10, half_t><<<(unsigned)(((size_t)n * 5 + 255) / 256), 256, 0, stream>>>(
      hb, P(32), P(33), P(34), P(35), xl, xr, n);
  edge_kernel<5, 10, 2><<<(unsigned)(((size_t)n * 40 + 255) / 256), 256, 0, stream>>>(
      xl, xr, start, deg, csrc, P(36), nullptr, nullptr, nullptr, nullptr, nullptr, hb, n);

  final_kernel<<<nblk, 256, 0, stream>>>(
      hb, P(37), P(38), P(39), P(40), P(41), P(42), P(43), P(44), P(45), (float*)d_out, n);
}

// Round 13
// 488.150 us; speedup vs baseline: 1.0950x; 1.0950x over previous
//
#include <hip/hip_runtime.h>

#define BN_EPS 1e-5f

typedef _Float16 half_t;
typedef _Float16 half2_t __attribute__((ext_vector_type(2)));

#define NBK_MAX 512   // max dst-buckets (256 dsts each) -> n <= 131072
#define EPB 8192      // edges per block in bucket scatter
#define REC 64        // xl record: 64 halves = 128 B, line-aligned
#define CAP 5120      // fixed per-bucket capacity (mean ~4350, +11 sigma)

#if __has_builtin(__builtin_amdgcn_fdot2)
#define DOT2(a, b, c) __builtin_amdgcn_fdot2((a), (b), (c), false)
#else
#define DOT2(a, b, c) fmaf((float)(a).x, (float)(b).x, fmaf((float)(a).y, (float)(b).y, (c)))
#endif

// ---------------- bucketed CSR build (fixed-capacity buckets, packed entries) ----------------

// K1: two-pass over this block's ei slice (L2-hot): count per bucket, reserve, place.
// bstage entry = (src << 8) | (dst & 255); bucket implied by slot (strided by CAP).
__global__ void __launch_bounds__(256) bucket_scatter_kernel(
    const int* __restrict__ ei, int* __restrict__ bcur, unsigned* __restrict__ bstage,
    int E, int etot, int nbk) {
  __shared__ int lh[NBK_MAX], lbase[NBK_MAX];
  int base = blockIdx.x * EPB;
  int cnt = min(EPB, etot - base);
  for (int i = threadIdx.x; i < nbk; i += 256) lh[i] = 0;
  __syncthreads();
  for (int i = threadIdx.x; i < cnt; i += 256) {
    int e = base + i;
    int d = (e < E) ? ei[E + e] : (e - E);
    atomicAdd(&lh[d >> 8], 1);
  }
  __syncthreads();
  for (int i = threadIdx.x; i < nbk; i += 256) {
    int c = lh[i];
    lbase[i] = c ? (i * CAP + atomicAdd(&bcur[i], c)) : 0;
    lh[i] = 0;  // becomes local run cursor
  }
  __syncthreads();
  for (int i = threadIdx.x; i < cnt; i += 256) {
    int e = base + i;
    int s, d;
    if (e < E) { s = ei[e]; d = ei[E + e]; } else { s = e - E; d = s; }
    int b = d >> 8;
    int r = atomicAdd(&lh[b], 1);
    bstage[lbase[b] + r] = ((unsigned)s << 8) | (unsigned)(d & 255);
  }
}

// K2: per-bucket degree count + in-bucket scan -> start/deg, then LDS-cursor placement
__global__ void __launch_bounds__(256) csr_finalize_kernel(
    const unsigned* __restrict__ bstage, const int* __restrict__ bcur,
    int* __restrict__ start, int* __restrict__ deg, int* __restrict__ csrc, int n) {
  __shared__ int ld[256];
  __shared__ int wsum[4];
  int b = blockIdx.x, tid = threadIdx.x;
  int d0 = b << 8;
  int p0 = b * CAP;
  int bc = bcur[b];
  ld[tid] = 0;
  __syncthreads();
  for (int p = p0 + tid; p < p0 + bc; p += 256)
    atomicAdd(&ld[bstage[p] & 255u], 1);
  __syncthreads();
  int v = ld[tid];
  int lane = tid & 63, wid = tid >> 6;
  int incl = v;
#pragma unroll
  for (int off = 1; off < 64; off <<= 1) {
    int t = __shfl_up(incl, off, 64);
    if (lane >= off) incl += t;
  }
  if (lane == 63) wsum[wid] = incl;
  __syncthreads();
  if (tid == 0) {
    int s = 0;
#pragma unroll
    for (int w = 0; w < 4; w++) { int t = wsum[w]; wsum[w] = s; s += t; }
  }
  __syncthreads();
  incl += wsum[wid];
  int st = p0 + incl - v;
  int i = d0 + tid;
  if (i < n) { start[i] = st; deg[i] = v; }
  __syncthreads();
  ld[tid] = st;  // cursor
  __syncthreads();
  for (int p = p0 + tid; p < p0 + bc; p += 256) {
    unsigned sd = bstage[p];
    int pos = atomicAdd(&ld[sd & 255u], 1);
    csrc[pos] = (int)(sd >> 8);
  }
}

// ---------------- node transform ----------------
// Input IT = float (layer 1) or half_t (hb). Each thread computes JT outputs for one node.
// xl (fp16, [n][REC] 128B records, head h at half-offset h*C) = x@Wl+bl
// xr (fp16, [n][HC]) = x@Wr+br

template <int CIN, int H, int C, int JT, typename IT>
__global__ void __launch_bounds__(256) transform_kernel(
    const IT* __restrict__ x, const float* __restrict__ Wl, const float* __restrict__ Wr,
    const float* __restrict__ bl, const float* __restrict__ br, half_t* __restrict__ xl,
    half_t* __restrict__ xr, int n) {
  constexpr int HC = H * C;
  constexpr int TPN = HC / JT;  // threads per node
  __shared__ float sW[2 * CIN * HC];
  for (int i = threadIdx.x; i < CIN * HC; i += blockDim.x) {
    sW[i] = Wl[i];
    sW[CIN * HC + i] = Wr[i];
  }
  __syncthreads();
  int idx = blockIdx.x * blockDim.x + threadIdx.x;
  if (idx >= n * TPN) return;
  int node = idx / TPN;
  int j0 = (idx - node * TPN) * JT;

  float al[JT], ar[JT];
#pragma unroll
  for (int jj = 0; jj < JT; jj++) {
    al[jj] = bl[j0 + jj];
    ar[jj] = br[j0 + jj];
  }
  float xrow[CIN];
  if constexpr (sizeof(IT) == 4) {
    const float2* xp = reinterpret_cast<const float2*>((const float*)x + (size_t)node * CIN);
#pragma unroll
    for (int k2 = 0; k2 < CIN / 2; k2++) {
      float2 v = xp[k2];
      xrow[2 * k2] = v.x;
      xrow[2 * k2 + 1] = v.y;
    }
  } else {
    const half2_t* xp = reinterpret_cast<const half2_t*>((const half_t*)x + (size_t)node * CIN);
#pragma unroll
    for (int k2 = 0; k2 < CIN / 2; k2++) {
      half2_t v = xp[k2];
      xrow[2 * k2] = (float)v.x;
      xrow[2 * k2 + 1] = (float)v.y;
    }
  }
#pragma unroll
  for (int k = 0; k < CIN; k++) {
    float xs = xrow[k];
#pragma unroll
    for (int jj = 0; jj < JT; jj++) {
      al[jj] = fmaf(xs, sW[k * HC + j0 + jj], al[jj]);
      ar[jj] = fmaf(xs, sW[CIN * HC + k * HC + j0 + jj], ar[jj]);
    }
  }
#pragma unroll
  for (int jj = 0; jj < JT; jj++) {
    int j = j0 + jj;
    xl[(size_t)node * REC + j] = (half_t)al[jj];   // heads packed: offset h*C+c == j
    xr[(size_t)node * HC + j] = (half_t)ar[jj];
  }
}

// ---------------- fused edge pass ----------------
// G=2 lanes cooperate on one (node, head): lane l takes edges l, l+2, ... then ONE
// shuffle-xor combine. 2x thread count lifts residency (R12 showed the TLP mechanism
// works; G=2 keeps prologue/reduce redundancy ~15%). Depth-3 row pipeline + 3-ahead
// index queue per lane. Packed-half2 math; den f32.
// MODE 0: +bias,BN  1: +bias,BN,ELU  2: raw. Output fp16.

#define PIDX(K) csrc[p0 + gl + 2 * (((K) < cnt_l) ? (K) : cnt_l - 1)]

#define ROW(B, IR)                                                                  \
  {                                                                                 \
    const uint* xp_ = reinterpret_cast<const uint*>(xlh + (size_t)(IR) * REC);      \
    _Pragma("unroll") for (int i_ = 0; i_ < C2; i_++) B[i_] = xp_[i_];              \
  }

#define COMP_ROW(B, M)                                                              \
  {                                                                                 \
    const half2_t* hp_ = reinterpret_cast<const half2_t*>(B);                       \
    float e_ = 0.f;                                                                 \
    _Pragma("unroll") for (int i = 0; i < C2; i++) {                                \
      half2_t m_ = hp_[i] + xr_h[i];                                                \
      half2_t mp_ = __builtin_elementwise_max(m_, h2z);                             \
      half2_t mn_ = __builtin_elementwise_min(m_, h2z);                             \
      m_ = mp_ + mn_ * h2lk;                                                        \
      e_ = DOT2(att_h[i], m_, e_);                                                  \
    }                                                                               \
    float ex_ = ((M) < cnt_l) ? __expf(e_) : 0.f;                                   \
    den += ex_;                                                                     \
    half_t exs_ = (half_t)ex_;                                                      \
    half2_t exv_ = {exs_, exs_};                                                    \
    _Pragma("unroll") for (int i = 0; i < C2; i++) acc[i] += exv_ * hp_[i];         \
  }

template <int H, int C, int MODE>
__global__ void __launch_bounds__(256) edge_kernel(
    const half_t* __restrict__ xl, const half_t* __restrict__ xr,
    const int* __restrict__ start, const int* __restrict__ deg,
    const int* __restrict__ csrc, const float* __restrict__ att,
    const float* __restrict__ bias, const float* __restrict__ g,
    const float* __restrict__ be, const float* __restrict__ rm,
    const float* __restrict__ rv, half_t* __restrict__ out, int n) {
  constexpr int HC = H * C;
  constexpr int C2 = C / 2;
  int t = blockIdx.x * blockDim.x + threadIdx.x;
  int gid = t >> 1;  // (node, head) group
  if (gid >= n * H) return;
  int gl = t & 1;
  int node = gid / H;
  int h = gid - node * H;

  const half2_t h2z = {(half_t)0.f, (half_t)0.f};
  const half2_t h2lk = {(half_t)0.2f, (half_t)0.2f};

  half2_t xr_h[C2], att_h[C2], acc[C2];
  const half2_t* xrp = reinterpret_cast<const half2_t*>(xr + (size_t)node * HC + h * C);
#pragma unroll
  for (int i = 0; i < C2; i++) {
    xr_h[i] = xrp[i];
    att_h[i] = half2_t{(half_t)att[h * C + 2 * i], (half_t)att[h * C + 2 * i + 1]};
    acc[i] = h2z;
  }
  float den = 0.f;

  int p0 = start[node];
  int cnt = deg[node];  // >= 1 (self-loop)
  int cnt_l = (cnt > gl) ? ((cnt - gl + 1) >> 1) : 0;  // this lane's edge count
  const half_t* xlh = xl + h * C;  // head slice within the 128B record

  if (cnt_l > 0) {
    uint B0[C2], B1[C2], B2[C2];
    int i0, i1, i2;
    i0 = PIDX(0); i1 = PIDX(1); i2 = PIDX(2);
    ROW(B0, i0) ROW(B1, i1) ROW(B2, i2)
    i0 = PIDX(3); i1 = PIDX(4); i2 = PIDX(5);
    int cnt3 = ((cnt_l + 2) / 3) * 3;
    for (int m = 0; m < cnt3; m += 3) {
      COMP_ROW(B0, m)     ROW(B0, i0) i0 = PIDX(m + 6);
      COMP_ROW(B1, m + 1) ROW(B1, i1) i1 = PIDX(m + 7);
      COMP_ROW(B2, m + 2) ROW(B2, i2) i2 = PIDX(m + 8);
    }
  }

  // combine the two lanes' partials (lanes of a pair are wave-adjacent)
  den += __shfl_xor(den, 1, 64);
#pragma unroll
  for (int i = 0; i < C2; i++) {
    int sv = __shfl_xor(__builtin_bit_cast(int, acc[i]), 1, 64);
    acc[i] += __builtin_bit_cast(half2_t, sv);
  }
  if (gl != 0) return;

  float inv = 1.f / den;
  uint* orow = reinterpret_cast<uint*>(out + (size_t)node * HC + h * C);
#pragma unroll
  for (int c2 = 0; c2 < C2; c2++) {
    half2_t ov;
#pragma unroll
    for (int q = 0; q < 2; q++) {
      float a = q ? (float)acc[c2].y : (float)acc[c2].x;
      float val = a * inv;
      if constexpr (MODE != 2) {
        int j = h * C + 2 * c2 + q;
        val += bias[j];
        float sc = g[j] * rsqrtf(rv[j] + BN_EPS);
        val = fmaf(sc, val - rm[j], be[j]);
        if constexpr (MODE == 1) val = (val > 0.f) ? val : expm1f(val);
      }
      if (q) ov.y = (half_t)val; else ov.x = (half_t)val;
    }
    orow[c2] = *reinterpret_cast<uint*>(&ov);
  }
}

// ---------------- layer-4 tail: mean over heads + bias + BN + mu/logvar heads ----------------

__global__ void final_kernel(const half_t* __restrict__ r4, const float* __restrict__ b4,
                             const float* __restrict__ g4, const float* __restrict__ be4,
                             const float* __restrict__ rm4, const float* __restrict__ rv4,
                             const float* __restrict__ Wmu, const float* __restrict__ bmu,
                             const float* __restrict__ Wlv, const float* __restrict__ blv,
                             float* __restrict__ out, int n) {
  int node = blockIdx.x * blockDim.x + threadIdx.x;
  if (node >= n) return;
  float hsum[10];
#pragma unroll
  for (int c = 0; c < 10; c++) hsum[c] = 0.f;
  const half2_t* r = reinterpret_cast<const half2_t*>(r4 + (size_t)node * 50);
  float rv_[50];
#pragma unroll
  for (int i = 0; i < 25; i++) {
    half2_t v = r[i];
    rv_[2 * i] = (float)v.x;
    rv_[2 * i + 1] = (float)v.y;
  }
#pragma unroll
  for (int h = 0; h < 5; h++)
#pragma unroll
    for (int c = 0; c < 10; c++) hsum[c] += rv_[h * 10 + c];
  float hv[10];
#pragma unroll
  for (int c = 0; c < 10; c++) {
    float v = hsum[c] * 0.2f + b4[c];
    float sc = g4[c] * rsqrtf(rv4[c] + BN_EPS);
    hv[c] = fmaf(sc, v - rm4[c], be4[c]);
  }
#pragma unroll
  for (int j = 0; j < 10; j++) {
    float mu = bmu[j], lv = blv[j];
#pragma unroll
    for (int c = 0; c < 10; c++) {
      mu = fmaf(hv[c], Wmu[c * 10 + j], mu);
      lv = fmaf(hv[c], Wlv[c * 10 + j], lv);
    }
    out[(size_t)node * 10 + j] = mu;
    out[(size_t)n * 10 + (size_t)node * 10 + j] = lv;
  }
}

// ---------------- launch ----------------

extern "C" void kernel_launch(void* const* d_in, const int* in_sizes, int n_in,
                              void* d_out, int out_size, void* d_ws, size_t ws_size,
                              hipStream_t stream) {
  const float* x = (const float*)d_in[0];
  const int* ei = (const int*)d_in[1];
  const int n = in_sizes[0] / 22;
  const int E = in_sizes[1] / 2;
  const int etot = E + n;
  const int nbk = (n + 255) >> 8;  // 256-dst buckets

  auto P = [&](int i) { return (const float*)d_in[i]; };

  char* ws = (char*)d_ws;
  size_t off = 0;
  auto alloc = [&](size_t bytes) -> void* {
    void* p = ws + off;
    off += (bytes + 255) & ~(size_t)255;
    return p;
  };
  half_t* xl = (half_t*)alloc((size_t)n * REC * 2);  // 12.8 MB, 128B-aligned records
  half_t* xr = (half_t*)alloc((size_t)n * 54 * 2);   // 10.8 MB
  half_t* hb = (half_t*)alloc((size_t)n * 54 * 2);   // 10.8 MB
  int* start = (int*)alloc((size_t)n * 4);
  int* deg = (int*)alloc((size_t)n * 4);
  int* csrc = (int*)alloc((size_t)nbk * CAP * 4);    // strided buckets (gaps ok)
  int* bcur = (int*)alloc((size_t)nbk * 4);
  // bstage (uint, 8 MB) aliases xl region (only live before transforms run)
  unsigned* bstage = (unsigned*)xl;

  unsigned bb = (unsigned)((etot + EPB - 1) / EPB);
  unsigned nblk = (unsigned)((n + 255) / 256);

  hipMemsetAsync(bcur, 0, (size_t)nbk * 4, stream);
  bucket_scatter_kernel<<<bb, 256, 0, stream>>>(ei, bcur, bstage, E, etot, nbk);
  csr_finalize_kernel<<<(unsigned)nbk, 256, 0, stream>>>(bstage, bcur, start, deg, csrc, n);

  // layer 1: cin=22, H=3, C=18, concat, BN+ELU
  transform_kernel<22, 3, 18, 6, float><<<(unsigned)(((size_t)n * 9 + 255) / 256), 256, 0, stream>>>(
      x, P(2), P(3), P(4), P(5), xl, xr, n);
  edge_kernel<3, 18, 1><<<(unsigned)(((size_t)n * 6 + 255) / 256), 256, 0, stream>>>(
      xl, xr, start, deg, csrc, P(6), P(7), P(8), P(9), P(10), P(11), hb, n);

  // layer 2: cin=54, H=3, C=14, concat, BN
  transform_kernel<54, 3, 14, 6, half_t><<<(unsigned)(((size_t)n * 7 + 255) / 256), 256, 0, stream>>>(
      hb, P(12), P(13), P(14), P(15), xl, xr, n);
  edge_kernel<3, 14, 0><<<(unsigned)(((size_t)n * 6 + 255) / 256), 256, 0, stream>>>(
      xl, xr, start, deg, csrc, P(16), P(17), P(18), P(19), P(20), P(21), hb, n);

  // layer 3: cin=42, H=3, C=12, concat, BN
  transform_kernel<42, 3, 12, 6, half_t><<<(unsigned)(((size_t)n * 6 + 255) / 256), 256, 0, stream>>>(
      hb, P(22), P(23), P(24), P(25), xl, xr, n);
  edge_kernel<3, 12, 0><<<(unsigned)(((size_t)n * 6 + 255) / 256), 256, 0, stream>>>(
      xl, xr, start, deg, csrc, P(26), P(27), P(28), P(29), P(30), P(31), hb, n);

  // layer 4: cin=36, H=5, C=10, mean over heads (raw; epilogue in final_kernel)
  transform_kernel<36, 5, 10, 10, half_t><<<(unsigned)(((size_t)n * 5 + 255) / 256), 256, 0, stream>>>(
      hb, P(32), P(33), P(34), P(35), xl, xr, n);
  edge_kernel<5, 10, 2><<<(unsigned)(((size_t)n * 10 + 255) / 256), 256, 0, stream>>>(
      xl, xr, start, deg, csrc, P(36), nullptr, nullptr, nullptr, nullptr, nullptr, hb, n);

  final_kernel<<<nblk, 256, 0, stream>>>(
      hb, P(37), P(38), P(39), P(40), P(41), P(42), P(43), P(44), P(45), (float*)d_out, n);
}